// Round 7
// baseline (23.131 us; speedup 1.0000x reference)
//
#include <hip/hip_runtime.h>
#include <math.h>

#define BLOCK 256

struct __align__(8) V2 { float x, y; };

__device__ __forceinline__ void box_corners(float x, float y, float hx, float hy,
                                            float c, float s, V2* out) {
    // CCW corners, matches reference _corners order
    const float cx = c * hx, sx = s * hx, cy = c * hy, sy = s * hy;
    out[0].x = x + cx - sy; out[0].y = y + sx + cy;
    out[1].x = x - cx - sy; out[1].y = y - sx + cy;
    out[2].x = x - cx + sy; out[2].y = y - sx - cy;
    out[3].x = x + cx + sy; out[3].y = y + sx - cy;
}

// Green's-theorem accumulation: sum of cross(p,q) over {edges of E clipped to
// convex CCW quad C}. Returns 2*area contribution. Register-only, fully
// unrolled, no dynamic indexing (rule #20 safe). Validated bitwise R3-R6.
__device__ __forceinline__ float clip_edges(const V2* E, const V2* C) {
    float acc = 0.f;
    #pragma unroll
    for (int e = 0; e < 4; ++e) {
        const V2 P = E[e], Q = E[(e + 1) & 3];
        const float dx = Q.x - P.x, dy = Q.y - P.y;
        float t0 = 0.f, t1 = 1.f;
        #pragma unroll
        for (int k = 0; k < 4; ++k) {
            const V2 c1 = C[k], c2 = C[(k + 1) & 3];
            const float ex = c2.x - c1.x, ey = c2.y - c1.y;
            // f(t) = a + t*b >= 0  <=> point inside half-plane of edge k
            const float a = ex * (P.y - c1.y) - ey * (P.x - c1.x);
            const float b = ex * dy - ey * dx;
            if (b > 1e-12f)        t0 = fmaxf(t0, -a / b);
            else if (b < -1e-12f)  t1 = fminf(t1, -a / b);
            else if (a < 0.f)      t1 = -2.f;   // parallel & outside -> empty
        }
        const float w = fmaxf(t1 - t0, 0.f);
        // cross(P+t0*d, P+t1*d) = (t1-t0)*cross(P,d)
        acc += w * (P.x * dy - P.y * dx);
    }
    return acc;
}

__global__ __launch_bounds__(BLOCK) void iou_row_kernel(
    const float* __restrict__ iou_pred,
    const float* __restrict__ box_pred,
    const float* __restrict__ box_gt,
    float* __restrict__ rowloss,
    int M)
{
    __shared__ float4 s_aux[512];    // {bx-ax, by-ay, bdx, bdy} cached at reject
    __shared__ float  s_yaw[512];    // yaw cached at reject -> phase 2 is LDS-only
    __shared__ int    s_n;
    __shared__ float  s_red[BLOCK / 64];

    const int tid  = threadIdx.x;
    const int lane = tid & 63;
    const int wid  = tid >> 6;
    const int i = blockIdx.x;

    if (tid == 0) s_n = 0;

    // hoisted: consumed only after the last barrier; hide latency here
    const float ip = iou_pred[i];

    // pred box (block-uniform -> scalar loads), re-centered at origin
    const float ax   = box_pred[i * 7 + 0];
    const float ay   = box_pred[i * 7 + 1];
    const float adx  = box_pred[i * 7 + 3];
    const float ady  = box_pred[i * 7 + 4];
    const float ayaw = box_pred[i * 7 + 6];
    const float ahx = 0.5f * adx, ahy = 0.5f * ady;
    const float area_a = adx * ady;
    const float ra = sqrtf(ahx * ahx + ahy * ahy);
    V2 CA[4];
    box_corners(0.f, 0.f, ahx, ahy, cosf(ayaw), sinf(ayaw), CA);
    __syncthreads();   // s_n = 0 visible to all waves

    // phase 1: circumradius reject; ballot compaction, 1 LDS atomic per wave.
    // All survivor fields (incl. yaw, exec-masked load) cached in LDS.
    for (int j = tid; j < M; j += BLOCK) {
        const float bx  = box_gt[j * 7 + 0];
        const float by  = box_gt[j * 7 + 1];
        const float bdx = box_gt[j * 7 + 3];
        const float bdy = box_gt[j * 7 + 4];
        const float rb = 0.5f * sqrtf(bdx * bdx + bdy * bdy);
        const float dx = bx - ax, dy = by - ay;
        const float rr = ra + rb;
        const bool pass = (dx * dx + dy * dy) <= rr * rr;
        const unsigned long long m = __ballot(pass);
        const int cnt = __popcll(m);
        int base = 0;
        if (lane == 0 && cnt) base = atomicAdd(&s_n, cnt);
        base = __shfl(base, 0, 64);
        if (pass) {
            const int pos = base + __popcll(m & ((1ull << lane) - 1ull));
            s_aux[pos] = make_float4(dx, dy, bdx, bdy);
            s_yaw[pos] = box_gt[j * 7 + 6];
        }
    }
    __syncthreads();

    // phase 2: pure LDS+VALU register-only intersection for survivors
    const int ns = s_n;
    float mymax = 0.f;
    for (int k = tid; k < ns; k += BLOCK) {
        const float4 aux = s_aux[k];
        const float byaw = s_yaw[k];
        V2 CB[4];
        box_corners(aux.x, aux.y, 0.5f * aux.z, 0.5f * aux.w,
                    cosf(byaw), sinf(byaw), CB);
        const float s2 = clip_edges(CA, CB) + clip_edges(CB, CA);
        const float inter = 0.5f * fmaxf(s2, 0.f);
        const float uni = fmaxf(area_a + aux.z * aux.w - inter, 1e-8f);
        mymax = fmaxf(mymax, inter / uni);
    }

    // per-wave shuffle max, then tiny cross-wave combine (1 barrier)
    #pragma unroll
    for (int off = 32; off > 0; off >>= 1)
        mymax = fmaxf(mymax, __shfl_xor(mymax, off, 64));
    if (lane == 0) s_red[wid] = mymax;
    __syncthreads();
    if (tid == 0) {
        const float mx = fmaxf(fmaxf(s_red[0], s_red[1]),
                               fmaxf(s_red[2], s_red[3]));
        const float target = 2.f * mx - 1.f;
        rowloss[i] = fabsf(ip - target);
    }
}

__global__ __launch_bounds__(256) void loss_reduce_kernel(
    const float* __restrict__ rowloss,
    const int* __restrict__ ntp,
    float* __restrict__ out,
    int N)
{
    const int tid = threadIdx.x;
    const int lane = tid & 63;
    const int wid = tid >> 6;
    __shared__ float s[4];
    float acc = 0.f;
    const int n4 = N >> 2;
    const float4* r4 = (const float4*)rowloss;
    for (int k = tid; k < n4; k += 256) {
        const float4 v = r4[k];
        acc += (v.x + v.y) + (v.z + v.w);
    }
    for (int k = (n4 << 2) + tid; k < N; k += 256) acc += rowloss[k];
    #pragma unroll
    for (int off = 32; off > 0; off >>= 1)
        acc += __shfl_xor(acc, off, 64);
    if (lane == 0) s[wid] = acc;
    __syncthreads();
    if (tid == 0)
        out[0] = (s[0] + s[1] + s[2] + s[3]) / ((float)ntp[0] + 1e-4f);
}

extern "C" void kernel_launch(void* const* d_in, const int* in_sizes, int n_in,
                              void* d_out, int out_size, void* d_ws, size_t ws_size,
                              hipStream_t stream) {
    const float* iou_pred = (const float*)d_in[0];
    const float* box_pred = (const float*)d_in[1];
    const float* box_gt   = (const float*)d_in[2];
    const int*   ntp      = (const int*)d_in[3];
    float* out     = (float*)d_out;
    float* rowloss = (float*)d_ws;

    const int N = in_sizes[0];        // iou_pred is (N,1)
    const int M = in_sizes[2] / 7;    // box_gt is (M,7)

    iou_row_kernel<<<N, BLOCK, 0, stream>>>(iou_pred, box_pred, box_gt, rowloss, M);
    loss_reduce_kernel<<<1, 256, 0, stream>>>(rowloss, ntp, out, N);
}

// Round 8
// 16.005 us; speedup vs baseline: 1.4453x; 1.4453x over previous
//
#include <hip/hip_runtime.h>
#include <math.h>

#define BLOCK 512          // 8 waves; each wave owns one pred row
#define WPB   8            // waves (rows) per block

struct __align__(8) V2 { float x, y; };

__device__ __forceinline__ void box_corners(float x, float y, float hx, float hy,
                                            float c, float s, V2* out) {
    // CCW corners, matches reference _corners order
    const float cx = c * hx, sx = s * hx, cy = c * hy, sy = s * hy;
    out[0].x = x + cx - sy; out[0].y = y + sx + cy;
    out[1].x = x - cx - sy; out[1].y = y - sx + cy;
    out[2].x = x - cx + sy; out[2].y = y - sx - cy;
    out[3].x = x + cx + sy; out[3].y = y + sx - cy;
}

// Green's-theorem accumulation: sum of cross(p,q) over {edges of E clipped to
// convex CCW quad C}. Returns 2*area contribution. Register-only, fully
// unrolled, no dynamic indexing (rule #20 safe). Validated bitwise R3-R7.
__device__ __forceinline__ float clip_edges(const V2* E, const V2* C) {
    float acc = 0.f;
    #pragma unroll
    for (int e = 0; e < 4; ++e) {
        const V2 P = E[e], Q = E[(e + 1) & 3];
        const float dx = Q.x - P.x, dy = Q.y - P.y;
        float t0 = 0.f, t1 = 1.f;
        #pragma unroll
        for (int k = 0; k < 4; ++k) {
            const V2 c1 = C[k], c2 = C[(k + 1) & 3];
            const float ex = c2.x - c1.x, ey = c2.y - c1.y;
            // f(t) = a + t*b >= 0  <=> point inside half-plane of edge k
            const float a = ex * (P.y - c1.y) - ey * (P.x - c1.x);
            const float b = ex * dy - ey * dx;
            if (b > 1e-12f)        t0 = fmaxf(t0, -a / b);
            else if (b < -1e-12f)  t1 = fminf(t1, -a / b);
            else if (a < 0.f)      t1 = -2.f;   // parallel & outside -> empty
        }
        const float w = fmaxf(t1 - t0, 0.f);
        // cross(P+t0*d, P+t1*d) = (t1-t0)*cross(P,d)
        acc += w * (P.x * dy - P.y * dx);
    }
    return acc;
}

__global__ __launch_bounds__(BLOCK) void iou_row_kernel(
    const float* __restrict__ iou_pred,
    const float* __restrict__ box_pred,
    const float* __restrict__ box_gt,
    float* __restrict__ rowloss,
    int M, int N)
{
    __shared__ int s_idx[WPB * 512];   // per-wave private segments; no barriers

    const int tid  = threadIdx.x;
    const int lane = tid & 63;
    const int wid  = tid >> 6;
    const int row  = blockIdx.x * WPB + wid;
    if (row >= N) return;              // wave-uniform exit

    int* const myidx = &s_idx[wid * 512];

    // hoisted: consumed at the very end; hide latency here
    const float ip = iou_pred[row];

    // pred box (wave-uniform values), re-centered at origin
    const float ax   = box_pred[row * 7 + 0];
    const float ay   = box_pred[row * 7 + 1];
    const float adx  = box_pred[row * 7 + 3];
    const float ady  = box_pred[row * 7 + 4];
    const float ayaw = box_pred[row * 7 + 6];
    const float ahx = 0.5f * adx, ahy = 0.5f * ady;
    const float area_a = adx * ady;
    const float ra = sqrtf(ahx * ahx + ahy * ahy);
    V2 CA[4];
    box_corners(0.f, 0.f, ahx, ahy, cosf(ayaw), sinf(ayaw), CA);

    // phase 1: circumradius reject; per-wave ballot compaction,
    // base counter lives in a (wave-uniform) register -- no atomics.
    int base = 0;
    for (int j0 = 0; j0 < M; j0 += 64) {
        const int j = j0 + lane;
        bool pass = false;
        if (j < M) {
            const float bx  = box_gt[j * 7 + 0];
            const float by  = box_gt[j * 7 + 1];
            const float bdx = box_gt[j * 7 + 3];
            const float bdy = box_gt[j * 7 + 4];
            const float rb = 0.5f * sqrtf(bdx * bdx + bdy * bdy);
            const float dx = bx - ax, dy = by - ay;
            const float rr = ra + rb;
            pass = (dx * dx + dy * dy) <= rr * rr;
        }
        const unsigned long long m = __ballot(pass);
        if (pass) myidx[base + __popcll(m & ((1ull << lane) - 1ull))] = j;
        base += __popcll(m);
    }
    // same-wave LDS RAW: compiler-ordered via lgkmcnt; no barrier needed

    // phase 2: register-only intersection for survivors
    float mymax = 0.f;
    for (int k = lane; k < base; k += 64) {
        const int j = myidx[k];
        const float bx   = box_gt[j * 7 + 0] - ax;
        const float by   = box_gt[j * 7 + 1] - ay;
        const float bdx  = box_gt[j * 7 + 3];
        const float bdy  = box_gt[j * 7 + 4];
        const float byaw = box_gt[j * 7 + 6];
        V2 CB[4];
        box_corners(bx, by, 0.5f * bdx, 0.5f * bdy, cosf(byaw), sinf(byaw), CB);
        const float s2 = clip_edges(CA, CB) + clip_edges(CB, CA);
        const float inter = 0.5f * fmaxf(s2, 0.f);
        const float uni = fmaxf(area_a + bdx * bdy - inter, 1e-8f);
        mymax = fmaxf(mymax, inter / uni);
    }

    // wave max-reduce; lane 0 writes the row loss
    #pragma unroll
    for (int off = 32; off > 0; off >>= 1)
        mymax = fmaxf(mymax, __shfl_xor(mymax, off, 64));
    if (lane == 0) {
        const float target = 2.f * mymax - 1.f;
        rowloss[row] = fabsf(ip - target);
    }
}

__global__ __launch_bounds__(256) void loss_reduce_kernel(
    const float* __restrict__ rowloss,
    const int* __restrict__ ntp,
    float* __restrict__ out,
    int N)
{
    const int tid = threadIdx.x;
    const int lane = tid & 63;
    const int wid = tid >> 6;
    __shared__ float s[4];
    float acc = 0.f;
    const int n4 = N >> 2;
    const float4* r4 = (const float4*)rowloss;
    for (int k = tid; k < n4; k += 256) {
        const float4 v = r4[k];
        acc += (v.x + v.y) + (v.z + v.w);
    }
    for (int k = (n4 << 2) + tid; k < N; k += 256) acc += rowloss[k];
    #pragma unroll
    for (int off = 32; off > 0; off >>= 1)
        acc += __shfl_xor(acc, off, 64);
    if (lane == 0) s[wid] = acc;
    __syncthreads();
    if (tid == 0)
        out[0] = (s[0] + s[1] + s[2] + s[3]) / ((float)ntp[0] + 1e-4f);
}

extern "C" void kernel_launch(void* const* d_in, const int* in_sizes, int n_in,
                              void* d_out, int out_size, void* d_ws, size_t ws_size,
                              hipStream_t stream) {
    const float* iou_pred = (const float*)d_in[0];
    const float* box_pred = (const float*)d_in[1];
    const float* box_gt   = (const float*)d_in[2];
    const int*   ntp      = (const int*)d_in[3];
    float* out     = (float*)d_out;
    float* rowloss = (float*)d_ws;

    const int N = in_sizes[0];        // iou_pred is (N,1)
    const int M = in_sizes[2] / 7;    // box_gt is (M,7)

    const int grid = (N + WPB - 1) / WPB;   // 256 blocks for N=2048
    iou_row_kernel<<<grid, BLOCK, 0, stream>>>(iou_pred, box_pred, box_gt,
                                               rowloss, M, N);
    loss_reduce_kernel<<<1, 256, 0, stream>>>(rowloss, ntp, out, N);
}